// Round 10
// baseline (903.657 us; speedup 1.0000x reference)
//
#include <hip/hip_runtime.h>
#include <math.h>

#define T_STEPS 2048
#define B_SZ 16
#define D_SZ 1024
#define N_SZ 64
#define M_ROWS (T_STEPS * B_SZ)   // 32768
#define NOUT (4 * N_SZ)           // 256
#define U_BLK 8
#define NBLK (T_STEPS / U_BLK)    // 256

typedef __attribute__((ext_vector_type(8))) short bf16x8;
typedef __attribute__((ext_vector_type(4))) float f32x4;

// ---------------------------------------------------------------------------
// DPP reduction: result uniform across the wave (readlane 63).
// ---------------------------------------------------------------------------
template <int CTRL, int RMASK, bool BC>
__device__ __forceinline__ float dpp_add(float v) {
  return v + __int_as_float(__builtin_amdgcn_update_dpp(
                 0, __float_as_int(v), CTRL, RMASK, 0xF, BC));
}
__device__ __forceinline__ float wave_red(float v) {
  v = dpp_add<0xB1, 0xF, true>(v);
  v = dpp_add<0x4E, 0xF, true>(v);
  v = dpp_add<0x141, 0xF, true>(v);
  v = dpp_add<0x140, 0xF, true>(v);
  v = dpp_add<0x142, 0xA, false>(v);
  v = dpp_add<0x143, 0xC, false>(v);
  return __int_as_float(__builtin_amdgcn_readlane(__float_as_int(v), 63));
}

__device__ __forceinline__ unsigned short f2bf(float f) {
  union { float f; unsigned u; } c; c.f = f;
  const unsigned r = c.u + 0x7FFFu + ((c.u >> 16) & 1u);   // RNE
  return (unsigned short)(r >> 16);
}

// ---------------------------------------------------------------------------
// Kernel 1: proj = x @ W^T via bf16 MFMA (unchanged from R7).
// ---------------------------------------------------------------------------
__global__ __launch_bounds__(256) void gemm_proj(const float* __restrict__ x,
                                                 const float* __restrict__ W,
                                                 float* __restrict__ proj) {
  __shared__ unsigned short Al[64][72];
  __shared__ unsigned short Bl[256][72];
  const int tid = threadIdx.x;
  const int lane = tid & 63;
  const int wv = tid >> 6;
  const int m0 = blockIdx.x * 64;
  const int nw0 = wv * 64;

  f32x4 acc[4][4];
#pragma unroll
  for (int m = 0; m < 4; ++m)
#pragma unroll
    for (int n = 0; n < 4; ++n) acc[m][n] = (f32x4){0.f, 0.f, 0.f, 0.f};

  const int arow = tid >> 2;
  const int akb = (tid & 3) * 16;

  for (int k0 = 0; k0 < D_SZ; k0 += 64) {
    {
      const float* src = &x[(size_t)(m0 + arow) * D_SZ + k0 + akb];
      unsigned short tmp[16];
#pragma unroll
      for (int c = 0; c < 4; ++c) {
        const float4 f = *reinterpret_cast<const float4*>(src + c * 4);
        tmp[c * 4 + 0] = f2bf(f.x); tmp[c * 4 + 1] = f2bf(f.y);
        tmp[c * 4 + 2] = f2bf(f.z); tmp[c * 4 + 3] = f2bf(f.w);
      }
      *reinterpret_cast<bf16x8*>(&Al[arow][akb]) =
          *reinterpret_cast<bf16x8*>(&tmp[0]);
      *reinterpret_cast<bf16x8*>(&Al[arow][akb + 8]) =
          *reinterpret_cast<bf16x8*>(&tmp[8]);
    }
    {
      const float* src = &W[(size_t)tid * D_SZ + k0];
#pragma unroll
      for (int h = 0; h < 4; ++h) {
        unsigned short tmp[16];
#pragma unroll
        for (int c = 0; c < 4; ++c) {
          const float4 f = *reinterpret_cast<const float4*>(src + h * 16 + c * 4);
          tmp[c * 4 + 0] = f2bf(f.x); tmp[c * 4 + 1] = f2bf(f.y);
          tmp[c * 4 + 2] = f2bf(f.z); tmp[c * 4 + 3] = f2bf(f.w);
        }
        *reinterpret_cast<bf16x8*>(&Bl[tid][h * 16]) =
            *reinterpret_cast<bf16x8*>(&tmp[0]);
        *reinterpret_cast<bf16x8*>(&Bl[tid][h * 16 + 8]) =
            *reinterpret_cast<bf16x8*>(&tmp[8]);
      }
    }
    __syncthreads();
    const int fr = lane & 15;
#pragma unroll
    for (int kk = 0; kk < 64; kk += 32) {
      const int kof = kk + (lane >> 4) * 8;
      bf16x8 af[4], bfr[4];
#pragma unroll
      for (int m = 0; m < 4; ++m)
        af[m] = *reinterpret_cast<const bf16x8*>(&Al[m * 16 + fr][kof]);
#pragma unroll
      for (int n = 0; n < 4; ++n)
        bfr[n] = *reinterpret_cast<const bf16x8*>(&Bl[nw0 + n * 16 + fr][kof]);
#pragma unroll
      for (int m = 0; m < 4; ++m)
#pragma unroll
        for (int n = 0; n < 4; ++n)
          acc[m][n] = __builtin_amdgcn_mfma_f32_16x16x32_bf16(
              af[m], bfr[n], acc[m][n], 0, 0, 0);
    }
    __syncthreads();
  }

  const int col = lane & 15;
  const int rb = (lane >> 4) * 4;
#pragma unroll
  for (int m = 0; m < 4; ++m)
#pragma unroll
    for (int n = 0; n < 4; ++n)
#pragma unroll
      for (int r = 0; r < 4; ++r)
        proj[(size_t)(m0 + m * 16 + rb + r) * NOUT + nw0 + n * 16 + col] =
            acc[m][n][r];
}

// ---------------------------------------------------------------------------
// Kernel 2: per (t,b) row, in-place repack: [ (kn,q) x64 | (v,dec) x64 ]
// ---------------------------------------------------------------------------
__global__ __launch_bounds__(256) void norm_gate(float* __restrict__ proj,
                                                 const float* __restrict__ b_gate) {
  const int wid = threadIdx.x >> 6;
  const int lane = threadIdx.x & 63;
  const int m = blockIdx.x * 4 + wid;
  float* p = proj + (size_t)m * NOUT;
  const float kf = p[lane];
  const float vf = p[64 + lane];
  const float qf = p[128 + lane];
  const float gf = p[192 + lane];
  const float bg = b_gate[lane];
  const float ss = wave_red(kf * kf);
  const float kn = kf / (sqrtf(ss) + 1e-6f);
  const float dec = 1.f / (1.f + expf(-(gf + bg)));
  asm volatile("s_waitcnt vmcnt(0)" ::: "memory");
  float2* pp = reinterpret_cast<float2*>(p);
  float2 a; a.x = kn; a.y = qf;
  float2 c; c.x = vf; c.y = dec;
  pp[lane] = a;
  pp[64 + lane] = c;
}

// ---------------------------------------------------------------------------
// Kernel 3: Gram precompute (unchanged).
// ---------------------------------------------------------------------------
__global__ __launch_bounds__(256) void gram_kernel(const float* __restrict__ proj,
                                                   float* __restrict__ gram) {
  const int wid = threadIdx.x >> 6;
  const int lane = threadIdx.x & 63;
  const int gw = blockIdx.x * 4 + wid;
  const int a = gw & 7;
  const int grp = gw >> 3;                  // b*NBLK + blk
  const int blk = grp & (NBLK - 1);
  const int b = grp >> 8;
  const int t0 = blk * U_BLK;
  const float2* base = reinterpret_cast<const float2*>(proj);

  float2 knq[8];
#pragma unroll
  for (int c = 0; c < 8; ++c)
    knq[c] = base[(size_t)((t0 + c) * B_SZ + b) * 128 + lane];
  const float2 mine = base[(size_t)((t0 + a) * B_SZ + b) * 128 + lane];

  float row[8];
#pragma unroll
  for (int c = 0; c < 8; ++c) {
    const float lhs = (c > a) ? mine.x : mine.y;
    row[c] = wave_red(lhs * knq[c].x);
  }
  if (lane == 0) {
    float* dst = gram + ((size_t)grp * 64 + a * 8);
    float4 r0, r1;
    r0.x = row[0]; r0.y = row[1]; r0.z = row[2]; r0.w = row[3];
    r1.x = row[4]; r1.y = row[5]; r1.z = row[6]; r1.w = row[7];
    *reinterpret_cast<float4*>(dst) = r0;
    *reinterpret_cast<float4*>(dst + 4) = r1;
  }
}

// ---------------------------------------------------------------------------
// Kernel 4: scan.  64 blocks x 1024 threads = 16 waves/block, 1 block/CU ->
// 4 independent chains per SIMD (TLP hides the serial-chain stalls).
// Block -> one b (bid & 15; the 4 blocks sharing b land on one XCD) and
// 16 chains i = (bid>>4)*16 + wid.  Compute per wave = R6's verified
// factored UT-transform; gram via uniform s_loads (SGPRs, R8-verified).
// 2-buffer LDS staging, each thread stages ONE float2 per iter.
// ---------------------------------------------------------------------------
__global__ __launch_bounds__(1024, 1) void scan_kernel(
    const float* __restrict__ proj, const float* __restrict__ gram,
    const float* __restrict__ S0, float* __restrict__ out,
    float* __restrict__ Sfin) {
  const int tid = threadIdx.x;
  const int wid = tid >> 6;          // 0..15
  const int lane = tid & 63;
  const int bid = blockIdx.x;
  const int b = bid & 15;
  const int i = ((bid >> 4) << 4) | wid;

  __shared__ float lds[2][U_BLK * 256];    // 2 x 8 KB

  float S = S0[(size_t)b * 4096 + i * 64 + lane];

  const int srow = tid >> 7;               // 0..7
  const int scol = tid & 127;              // float2 index 0..127
  float2 st;

#define GLOAD(blkv)                                                           \
  st = *reinterpret_cast<const float2*>(                                      \
      &proj[((size_t)(((blkv) * U_BLK + srow) * B_SZ + b)) * NOUT + scol * 2]);

#define LWRITE(bufv)                                                          \
  *reinterpret_cast<float2*>(&lds[bufv][srow * 256 + scol * 2]) = st;

  GLOAD(0)
  LWRITE(0)
  __syncthreads();

  for (int blk = 0; blk < NBLK; ++blk) {
    const int buf = blk & 1;
    if (blk + 1 < NBLK) GLOAD(blk + 1)

    // gram scalars: uniform address -> s_loads into SGPRs
    const float* gp = gram + (((size_t)b * NBLK + blk) << 6);
    float g[64];
#pragma unroll
    for (int z = 0; z < 64; ++z) g[z] = gp[z];

    // per-step vectors from LDS
    float2 knqv[8], vdv[8];
#pragma unroll
    for (int u = 0; u < 8; ++u) {
      knqv[u] = *reinterpret_cast<const float2*>(&lds[buf][u * 256 + lane * 2]);
      vdv[u] = *reinterpret_cast<const float2*>(&lds[buf][u * 256 + 128 + i * 2]);
    }

    // 16 independent reductions
    float acc[8], sac[8];
#pragma unroll
    for (int u = 0; u < 8; ++u) acc[u] = wave_red(S * knqv[u].x);
#pragma unroll
    for (int u = 0; u < 8; ++u) sac[u] = wave_red(S * knqv[u].y);

    // prefix products + reciprocals
    float c[9], rc[8];
    c[0] = 1.f;
#pragma unroll
    for (int u = 0; u < 8; ++u) {
      c[u + 1] = c[u] * vdv[u].y;
      rc[u] = __builtin_amdgcn_rcpf(c[u + 1]);
    }

    // factored UT-transform recurrence (verified R6)
    float dp[8], sqv[8];
#pragma unroll
    for (int w = 0; w < 8; ++w) {
      const float d = fmaf(-c[w], acc[w], vdv[w].x);
      dp[w] = d * rc[w];
      sqv[w] = fmaf(c[w + 1], sac[w], d * g[w * 8 + w]);
#pragma unroll
      for (int u = w + 1; u < 8; ++u) {
        acc[u] = fmaf(dp[w], g[w * 8 + u], acc[u]);   // G[w][u]
        sac[u] = fmaf(dp[w], g[u * 8 + w], sac[u]);   // H[u][w]
      }
    }
    float tacc = S;
#pragma unroll
    for (int w = 0; w < 8; ++w) tacc = fmaf(dp[w], knqv[w].x, tacc);
    S = c[8] * tacc;

    if (lane == 0) {
      const size_t ob = (size_t)blk * U_BLK * (B_SZ * N_SZ) + b * N_SZ + i;
#pragma unroll
      for (int u = 0; u < 8; ++u)
        out[ob + (size_t)u * (B_SZ * N_SZ)] = sqv[u];   // raw sq; silu later
    }

    if (blk + 1 < NBLK) LWRITE(buf ^ 1)
    __syncthreads();
  }

  Sfin[(size_t)b * 4096 + i * 64 + lane] = S;
#undef GLOAD
#undef LWRITE
}

// ---------------------------------------------------------------------------
// Kernel 5: out <- sq^2 * sigmoid(sq).  2048*256*4 = 2,097,152 elems exactly.
// ---------------------------------------------------------------------------
__global__ __launch_bounds__(256) void silu_pp(float* __restrict__ o) {
  const size_t idx = ((size_t)blockIdx.x * 256 + threadIdx.x) * 4;
  float4 v = *reinterpret_cast<float4*>(&o[idx]);
  v.x = v.x * v.x * __fdividef(1.f, 1.f + __expf(-v.x));
  v.y = v.y * v.y * __fdividef(1.f, 1.f + __expf(-v.y));
  v.z = v.z * v.z * __fdividef(1.f, 1.f + __expf(-v.z));
  v.w = v.w * v.w * __fdividef(1.f, 1.f + __expf(-v.w));
  *reinterpret_cast<float4*>(&o[idx]) = v;
}

// ---------------------------------------------------------------------------
extern "C" void kernel_launch(void* const* d_in, const int* in_sizes, int n_in,
                              void* d_out, int out_size, void* d_ws, size_t ws_size,
                              hipStream_t stream) {
  const float* x      = (const float*)d_in[0];
  const float* S0     = (const float*)d_in[1];
  const float* W      = (const float*)d_in[2];
  const float* b_gate = (const float*)d_in[3];
  float* out  = (float*)d_out;
  float* proj = (float*)d_ws;                       // 33.55 MB
  float* gram = (float*)((char*)d_ws + (size_t)M_ROWS * NOUT * 4);  // +1 MB

  hipLaunchKernelGGL(gemm_proj, dim3(M_ROWS / 64), dim3(256), 0, stream,
                     x, W, proj);
  hipLaunchKernelGGL(norm_gate, dim3(M_ROWS / 4), dim3(256), 0, stream,
                     proj, b_gate);
  hipLaunchKernelGGL(gram_kernel, dim3(32768 / 4), dim3(256), 0, stream,
                     proj, gram);
  hipLaunchKernelGGL(scan_kernel, dim3(64), dim3(1024), 0, stream,
                     proj, gram, S0, out, out + (size_t)T_STEPS * B_SZ * N_SZ);
  hipLaunchKernelGGL(silu_pp, dim3(2048), dim3(256), 0, stream, out);
}

// Round 11
// 558.646 us; speedup vs baseline: 1.6176x; 1.6176x over previous
//
#include <hip/hip_runtime.h>
#include <math.h>

#define T_STEPS 2048
#define B_SZ 16
#define D_SZ 1024
#define N_SZ 64
#define M_ROWS (T_STEPS * B_SZ)   // 32768
#define NOUT (4 * N_SZ)           // 256
#define U_BLK 8
#define NBLK (T_STEPS / U_BLK)    // 256

typedef __attribute__((ext_vector_type(8))) short bf16x8;
typedef __attribute__((ext_vector_type(4))) float f32x4;

// ---------------------------------------------------------------------------
// DPP reduction: result uniform across the wave (readlane 63).
// ---------------------------------------------------------------------------
template <int CTRL, int RMASK, bool BC>
__device__ __forceinline__ float dpp_add(float v) {
  return v + __int_as_float(__builtin_amdgcn_update_dpp(
                 0, __float_as_int(v), CTRL, RMASK, 0xF, BC));
}
__device__ __forceinline__ float wave_red(float v) {
  v = dpp_add<0xB1, 0xF, true>(v);
  v = dpp_add<0x4E, 0xF, true>(v);
  v = dpp_add<0x141, 0xF, true>(v);
  v = dpp_add<0x140, 0xF, true>(v);
  v = dpp_add<0x142, 0xA, false>(v);
  v = dpp_add<0x143, 0xC, false>(v);
  return __int_as_float(__builtin_amdgcn_readlane(__float_as_int(v), 63));
}

__device__ __forceinline__ unsigned short f2bf(float f) {
  union { float f; unsigned u; } c; c.f = f;
  const unsigned r = c.u + 0x7FFFu + ((c.u >> 16) & 1u);   // RNE
  return (unsigned short)(r >> 16);
}

// ---------------------------------------------------------------------------
// Kernel 1: proj = x @ W^T via bf16 MFMA (unchanged from R7).
// ---------------------------------------------------------------------------
__global__ __launch_bounds__(256) void gemm_proj(const float* __restrict__ x,
                                                 const float* __restrict__ W,
                                                 float* __restrict__ proj) {
  __shared__ unsigned short Al[64][72];
  __shared__ unsigned short Bl[256][72];
  const int tid = threadIdx.x;
  const int lane = tid & 63;
  const int wv = tid >> 6;
  const int m0 = blockIdx.x * 64;
  const int nw0 = wv * 64;

  f32x4 acc[4][4];
#pragma unroll
  for (int m = 0; m < 4; ++m)
#pragma unroll
    for (int n = 0; n < 4; ++n) acc[m][n] = (f32x4){0.f, 0.f, 0.f, 0.f};

  const int arow = tid >> 2;
  const int akb = (tid & 3) * 16;

  for (int k0 = 0; k0 < D_SZ; k0 += 64) {
    {
      const float* src = &x[(size_t)(m0 + arow) * D_SZ + k0 + akb];
      unsigned short tmp[16];
#pragma unroll
      for (int c = 0; c < 4; ++c) {
        const float4 f = *reinterpret_cast<const float4*>(src + c * 4);
        tmp[c * 4 + 0] = f2bf(f.x); tmp[c * 4 + 1] = f2bf(f.y);
        tmp[c * 4 + 2] = f2bf(f.z); tmp[c * 4 + 3] = f2bf(f.w);
      }
      *reinterpret_cast<bf16x8*>(&Al[arow][akb]) =
          *reinterpret_cast<bf16x8*>(&tmp[0]);
      *reinterpret_cast<bf16x8*>(&Al[arow][akb + 8]) =
          *reinterpret_cast<bf16x8*>(&tmp[8]);
    }
    {
      const float* src = &W[(size_t)tid * D_SZ + k0];
#pragma unroll
      for (int h = 0; h < 4; ++h) {
        unsigned short tmp[16];
#pragma unroll
        for (int c = 0; c < 4; ++c) {
          const float4 f = *reinterpret_cast<const float4*>(src + h * 16 + c * 4);
          tmp[c * 4 + 0] = f2bf(f.x); tmp[c * 4 + 1] = f2bf(f.y);
          tmp[c * 4 + 2] = f2bf(f.z); tmp[c * 4 + 3] = f2bf(f.w);
        }
        *reinterpret_cast<bf16x8*>(&Bl[tid][h * 16]) =
            *reinterpret_cast<bf16x8*>(&tmp[0]);
        *reinterpret_cast<bf16x8*>(&Bl[tid][h * 16 + 8]) =
            *reinterpret_cast<bf16x8*>(&tmp[8]);
      }
    }
    __syncthreads();
    const int fr = lane & 15;
#pragma unroll
    for (int kk = 0; kk < 64; kk += 32) {
      const int kof = kk + (lane >> 4) * 8;
      bf16x8 af[4], bfr[4];
#pragma unroll
      for (int m = 0; m < 4; ++m)
        af[m] = *reinterpret_cast<const bf16x8*>(&Al[m * 16 + fr][kof]);
#pragma unroll
      for (int n = 0; n < 4; ++n)
        bfr[n] = *reinterpret_cast<const bf16x8*>(&Bl[nw0 + n * 16 + fr][kof]);
#pragma unroll
      for (int m = 0; m < 4; ++m)
#pragma unroll
        for (int n = 0; n < 4; ++n)
          acc[m][n] = __builtin_amdgcn_mfma_f32_16x16x32_bf16(
              af[m], bfr[n], acc[m][n], 0, 0, 0);
    }
    __syncthreads();
  }

  const int col = lane & 15;
  const int rb = (lane >> 4) * 4;
#pragma unroll
  for (int m = 0; m < 4; ++m)
#pragma unroll
    for (int n = 0; n < 4; ++n)
#pragma unroll
      for (int r = 0; r < 4; ++r)
        proj[(size_t)(m0 + m * 16 + rb + r) * NOUT + nw0 + n * 16 + col] =
            acc[m][n][r];
}

// ---------------------------------------------------------------------------
// Kernel 2: per (t,b) row, in-place repack: [ (kn,q) x64 | (v,dec) x64 ]
// ---------------------------------------------------------------------------
__global__ __launch_bounds__(256) void norm_gate(float* __restrict__ proj,
                                                 const float* __restrict__ b_gate) {
  const int wid = threadIdx.x >> 6;
  const int lane = threadIdx.x & 63;
  const int m = blockIdx.x * 4 + wid;
  float* p = proj + (size_t)m * NOUT;
  const float kf = p[lane];
  const float vf = p[64 + lane];
  const float qf = p[128 + lane];
  const float gf = p[192 + lane];
  const float bg = b_gate[lane];
  const float ss = wave_red(kf * kf);
  const float kn = kf / (sqrtf(ss) + 1e-6f);
  const float dec = 1.f / (1.f + expf(-(gf + bg)));
  asm volatile("s_waitcnt vmcnt(0)" ::: "memory");
  float2* pp = reinterpret_cast<float2*>(p);
  float2 a; a.x = kn; a.y = qf;
  float2 c; c.x = vf; c.y = dec;
  pp[lane] = a;
  pp[64 + lane] = c;
}

// ---------------------------------------------------------------------------
// Kernel 3: Gram precompute (unchanged).
// ---------------------------------------------------------------------------
__global__ __launch_bounds__(256) void gram_kernel(const float* __restrict__ proj,
                                                   float* __restrict__ gram) {
  const int wid = threadIdx.x >> 6;
  const int lane = threadIdx.x & 63;
  const int gw = blockIdx.x * 4 + wid;
  const int a = gw & 7;
  const int grp = gw >> 3;                  // b*NBLK + blk
  const int blk = grp & (NBLK - 1);
  const int b = grp >> 8;
  const int t0 = blk * U_BLK;
  const float2* base = reinterpret_cast<const float2*>(proj);

  float2 knq[8];
#pragma unroll
  for (int c = 0; c < 8; ++c)
    knq[c] = base[(size_t)((t0 + c) * B_SZ + b) * 128 + lane];
  const float2 mine = base[(size_t)((t0 + a) * B_SZ + b) * 128 + lane];

  float row[8];
#pragma unroll
  for (int c = 0; c < 8; ++c) {
    const float lhs = (c > a) ? mine.x : mine.y;
    row[c] = wave_red(lhs * knq[c].x);
  }
  if (lane == 0) {
    float* dst = gram + ((size_t)grp * 64 + a * 8);
    float4 r0, r1;
    r0.x = row[0]; r0.y = row[1]; r0.z = row[2]; r0.w = row[3];
    r1.x = row[4]; r1.y = row[5]; r1.z = row[6]; r1.w = row[7];
    *reinterpret_cast<float4*>(dst) = r0;
    *reinterpret_cast<float4*>(dst + 4) = r1;
  }
}

// ---------------------------------------------------------------------------
// Kernel 4: scan.  1024 blocks x 64 threads = 1 wave per chain (b,i).
// NO LDS, NO barriers.  knq rows: coalesced lane-indexed loads, ping-pong
// prefetched 2-deep in registers (waves_per_eu(1) licenses high VGPR).
// vd rows + gram: wave-uniform addresses -> s_load into SGPRs (off the
// VALU chain; latency hidden under the 16 reductions).
// b = (bid&7)|((bid>>9)<<3): 64 blocks sharing b sit on one XCD (L2-hot).
// Compute = R6-verified factored UT-transform recurrence.
// ---------------------------------------------------------------------------
__global__ __launch_bounds__(64, 1) __attribute__((amdgpu_waves_per_eu(1)))
void scan_kernel(const float* __restrict__ proj, const float* __restrict__ gram,
                 const float* __restrict__ S0, float* __restrict__ out,
                 float* __restrict__ Sfin) {
  const int lane = threadIdx.x;
  const int bid = blockIdx.x;
  const int b = (bid & 7) | ((bid >> 9) << 3);
  const int i = (bid >> 3) & 63;

  float S = S0[(size_t)b * 4096 + i * 64 + lane];
  const float2* base = reinterpret_cast<const float2*>(proj);  // row = 128 f2

#define LOADK(knq, blkv)                                                      \
  {                                                                           \
    _Pragma("unroll")                                                         \
    for (int u = 0; u < 8; ++u)                                               \
      knq[u] = base[(size_t)(((blkv) * U_BLK + u) * B_SZ + b) * 128 + lane];  \
  }

#define PROC(knq, blkv)                                                       \
  {                                                                           \
    /* uniform rows: v,dec pairs + gram -> SGPRs via s_load */                \
    float2 vdv[8];                                                            \
    _Pragma("unroll")                                                         \
    for (int u = 0; u < 8; ++u)                                               \
      vdv[u] = base[(size_t)(((blkv) * U_BLK + u) * B_SZ + b) * 128 + 64 + i];\
    const float* gp = gram + (((size_t)b * NBLK + (blkv)) << 6);              \
    float g[64];                                                              \
    _Pragma("unroll")                                                         \
    for (int z = 0; z < 64; ++z) g[z] = gp[z];                                \
    float acc[8], sac[8];                                                     \
    _Pragma("unroll")                                                         \
    for (int u = 0; u < 8; ++u) acc[u] = wave_red(S * knq[u].x);              \
    _Pragma("unroll")                                                         \
    for (int u = 0; u < 8; ++u) sac[u] = wave_red(S * knq[u].y);              \
    float c[9], rc[8];                                                        \
    c[0] = 1.f;                                                               \
    _Pragma("unroll")                                                         \
    for (int u = 0; u < 8; ++u) {                                             \
      c[u + 1] = c[u] * vdv[u].y;                                             \
      rc[u] = __builtin_amdgcn_rcpf(c[u + 1]);                                \
    }                                                                         \
    float dp[8], sqv[8];                                                      \
    _Pragma("unroll")                                                         \
    for (int w = 0; w < 8; ++w) {                                             \
      const float d = fmaf(-c[w], acc[w], vdv[w].x);                          \
      dp[w] = d * rc[w];                                                      \
      sqv[w] = fmaf(c[w + 1], sac[w], d * g[w * 8 + w]);                      \
      _Pragma("unroll")                                                       \
      for (int u = w + 1; u < 8; ++u) {                                       \
        acc[u] = fmaf(dp[w], g[w * 8 + u], acc[u]);                           \
        sac[u] = fmaf(dp[w], g[u * 8 + w], sac[u]);                           \
      }                                                                       \
    }                                                                         \
    float tacc = S;                                                           \
    _Pragma("unroll")                                                         \
    for (int w = 0; w < 8; ++w) tacc = fmaf(dp[w], knq[w].x, tacc);           \
    S = c[8] * tacc;                                                          \
    if (lane == 0) {                                                          \
      const size_t ob = (size_t)(blkv) * U_BLK * (B_SZ * N_SZ) + b * N_SZ + i;\
      _Pragma("unroll")                                                       \
      for (int u = 0; u < 8; ++u)                                             \
        out[ob + (size_t)u * (B_SZ * N_SZ)] = sqv[u];                         \
    }                                                                         \
  }

  float2 ka[8], kb[8];
  LOADK(ka, 0)
  for (int blk = 0; blk < NBLK; blk += 2) {
    LOADK(kb, blk + 1)
    PROC(ka, blk)
    if (blk + 2 < NBLK) LOADK(ka, blk + 2)
    PROC(kb, blk + 1)
  }

  Sfin[(size_t)b * 4096 + i * 64 + lane] = S;
#undef LOADK
#undef PROC
}

// ---------------------------------------------------------------------------
// Kernel 5: out <- sq^2 * sigmoid(sq).  2048*256*4 = 2,097,152 elems exactly.
// ---------------------------------------------------------------------------
__global__ __launch_bounds__(256) void silu_pp(float* __restrict__ o) {
  const size_t idx = ((size_t)blockIdx.x * 256 + threadIdx.x) * 4;
  float4 v = *reinterpret_cast<float4*>(&o[idx]);
  v.x = v.x * v.x * __fdividef(1.f, 1.f + __expf(-v.x));
  v.y = v.y * v.y * __fdividef(1.f, 1.f + __expf(-v.y));
  v.z = v.z * v.z * __fdividef(1.f, 1.f + __expf(-v.z));
  v.w = v.w * v.w * __fdividef(1.f, 1.f + __expf(-v.w));
  *reinterpret_cast<float4*>(&o[idx]) = v;
}

// ---------------------------------------------------------------------------
extern "C" void kernel_launch(void* const* d_in, const int* in_sizes, int n_in,
                              void* d_out, int out_size, void* d_ws, size_t ws_size,
                              hipStream_t stream) {
  const float* x      = (const float*)d_in[0];
  const float* S0     = (const float*)d_in[1];
  const float* W      = (const float*)d_in[2];
  const float* b_gate = (const float*)d_in[3];
  float* out  = (float*)d_out;
  float* proj = (float*)d_ws;                       // 33.55 MB
  float* gram = (float*)((char*)d_ws + (size_t)M_ROWS * NOUT * 4);  // +1 MB

  hipLaunchKernelGGL(gemm_proj, dim3(M_ROWS / 64), dim3(256), 0, stream,
                     x, W, proj);
  hipLaunchKernelGGL(norm_gate, dim3(M_ROWS / 4), dim3(256), 0, stream,
                     proj, b_gate);
  hipLaunchKernelGGL(gram_kernel, dim3(32768 / 4), dim3(256), 0, stream,
                     proj, gram);
  hipLaunchKernelGGL(scan_kernel, dim3(1024), dim3(64), 0, stream,
                     proj, gram, S0, out, out + (size_t)T_STEPS * B_SZ * N_SZ);
  hipLaunchKernelGGL(silu_pp, dim3(2048), dim3(256), 0, stream, out);
}

// Round 12
// 548.218 us; speedup vs baseline: 1.6484x; 1.0190x over previous
//
#include <hip/hip_runtime.h>
#include <math.h>

#define T_STEPS 2048
#define B_SZ 16
#define D_SZ 1024
#define N_SZ 64
#define M_ROWS (T_STEPS * B_SZ)   // 32768
#define NOUT (4 * N_SZ)           // 256
#define U_BLK 8
#define NBLK (T_STEPS / U_BLK)    // 256

typedef __attribute__((ext_vector_type(8))) short bf16x8;
typedef __attribute__((ext_vector_type(4))) float f32x4;

// ---------------------------------------------------------------------------
// DPP reduction: result uniform across the wave (readlane 63).
// ---------------------------------------------------------------------------
template <int CTRL, int RMASK, bool BC>
__device__ __forceinline__ float dpp_add(float v) {
  return v + __int_as_float(__builtin_amdgcn_update_dpp(
                 0, __float_as_int(v), CTRL, RMASK, 0xF, BC));
}
__device__ __forceinline__ float wave_red(float v) {
  v = dpp_add<0xB1, 0xF, true>(v);
  v = dpp_add<0x4E, 0xF, true>(v);
  v = dpp_add<0x141, 0xF, true>(v);
  v = dpp_add<0x140, 0xF, true>(v);
  v = dpp_add<0x142, 0xA, false>(v);
  v = dpp_add<0x143, 0xC, false>(v);
  return __int_as_float(__builtin_amdgcn_readlane(__float_as_int(v), 63));
}

__device__ __forceinline__ unsigned short f2bf(float f) {
  union { float f; unsigned u; } c; c.f = f;
  const unsigned r = c.u + 0x7FFFu + ((c.u >> 16) & 1u);   // RNE
  return (unsigned short)(r >> 16);
}

// ---------------------------------------------------------------------------
// Kernel 1: proj = x @ W^T via bf16 MFMA (unchanged from R7).
// ---------------------------------------------------------------------------
__global__ __launch_bounds__(256) void gemm_proj(const float* __restrict__ x,
                                                 const float* __restrict__ W,
                                                 float* __restrict__ proj) {
  __shared__ unsigned short Al[64][72];
  __shared__ unsigned short Bl[256][72];
  const int tid = threadIdx.x;
  const int lane = tid & 63;
  const int wv = tid >> 6;
  const int m0 = blockIdx.x * 64;
  const int nw0 = wv * 64;

  f32x4 acc[4][4];
#pragma unroll
  for (int m = 0; m < 4; ++m)
#pragma unroll
    for (int n = 0; n < 4; ++n) acc[m][n] = (f32x4){0.f, 0.f, 0.f, 0.f};

  const int arow = tid >> 2;
  const int akb = (tid & 3) * 16;

  for (int k0 = 0; k0 < D_SZ; k0 += 64) {
    {
      const float* src = &x[(size_t)(m0 + arow) * D_SZ + k0 + akb];
      unsigned short tmp[16];
#pragma unroll
      for (int c = 0; c < 4; ++c) {
        const float4 f = *reinterpret_cast<const float4*>(src + c * 4);
        tmp[c * 4 + 0] = f2bf(f.x); tmp[c * 4 + 1] = f2bf(f.y);
        tmp[c * 4 + 2] = f2bf(f.z); tmp[c * 4 + 3] = f2bf(f.w);
      }
      *reinterpret_cast<bf16x8*>(&Al[arow][akb]) =
          *reinterpret_cast<bf16x8*>(&tmp[0]);
      *reinterpret_cast<bf16x8*>(&Al[arow][akb + 8]) =
          *reinterpret_cast<bf16x8*>(&tmp[8]);
    }
    {
      const float* src = &W[(size_t)tid * D_SZ + k0];
#pragma unroll
      for (int h = 0; h < 4; ++h) {
        unsigned short tmp[16];
#pragma unroll
        for (int c = 0; c < 4; ++c) {
          const float4 f = *reinterpret_cast<const float4*>(src + h * 16 + c * 4);
          tmp[c * 4 + 0] = f2bf(f.x); tmp[c * 4 + 1] = f2bf(f.y);
          tmp[c * 4 + 2] = f2bf(f.z); tmp[c * 4 + 3] = f2bf(f.w);
        }
        *reinterpret_cast<bf16x8*>(&Bl[tid][h * 16]) =
            *reinterpret_cast<bf16x8*>(&tmp[0]);
        *reinterpret_cast<bf16x8*>(&Bl[tid][h * 16 + 8]) =
            *reinterpret_cast<bf16x8*>(&tmp[8]);
      }
    }
    __syncthreads();
    const int fr = lane & 15;
#pragma unroll
    for (int kk = 0; kk < 64; kk += 32) {
      const int kof = kk + (lane >> 4) * 8;
      bf16x8 af[4], bfr[4];
#pragma unroll
      for (int m = 0; m < 4; ++m)
        af[m] = *reinterpret_cast<const bf16x8*>(&Al[m * 16 + fr][kof]);
#pragma unroll
      for (int n = 0; n < 4; ++n)
        bfr[n] = *reinterpret_cast<const bf16x8*>(&Bl[nw0 + n * 16 + fr][kof]);
#pragma unroll
      for (int m = 0; m < 4; ++m)
#pragma unroll
        for (int n = 0; n < 4; ++n)
          acc[m][n] = __builtin_amdgcn_mfma_f32_16x16x32_bf16(
              af[m], bfr[n], acc[m][n], 0, 0, 0);
    }
    __syncthreads();
  }

  const int col = lane & 15;
  const int rb = (lane >> 4) * 4;
#pragma unroll
  for (int m = 0; m < 4; ++m)
#pragma unroll
    for (int n = 0; n < 4; ++n)
#pragma unroll
      for (int r = 0; r < 4; ++r)
        proj[(size_t)(m0 + m * 16 + rb + r) * NOUT + nw0 + n * 16 + col] =
            acc[m][n][r];
}

// ---------------------------------------------------------------------------
// Kernel 2: per (t,b) row, in-place repack: [ (kn,q) x64 | (v,dec) x64 ]
// ---------------------------------------------------------------------------
__global__ __launch_bounds__(256) void norm_gate(float* __restrict__ proj,
                                                 const float* __restrict__ b_gate) {
  const int wid = threadIdx.x >> 6;
  const int lane = threadIdx.x & 63;
  const int m = blockIdx.x * 4 + wid;
  float* p = proj + (size_t)m * NOUT;
  const float kf = p[lane];
  const float vf = p[64 + lane];
  const float qf = p[128 + lane];
  const float gf = p[192 + lane];
  const float bg = b_gate[lane];
  const float ss = wave_red(kf * kf);
  const float kn = kf / (sqrtf(ss) + 1e-6f);
  const float dec = 1.f / (1.f + expf(-(gf + bg)));
  asm volatile("s_waitcnt vmcnt(0)" ::: "memory");
  float2* pp = reinterpret_cast<float2*>(p);
  float2 a; a.x = kn; a.y = qf;
  float2 c; c.x = vf; c.y = dec;
  pp[lane] = a;
  pp[64 + lane] = c;
}

// ---------------------------------------------------------------------------
// Kernel 3: Gram precompute (unchanged).
// ---------------------------------------------------------------------------
__global__ __launch_bounds__(256) void gram_kernel(const float* __restrict__ proj,
                                                   float* __restrict__ gram) {
  const int wid = threadIdx.x >> 6;
  const int lane = threadIdx.x & 63;
  const int gw = blockIdx.x * 4 + wid;
  const int a = gw & 7;
  const int grp = gw >> 3;                  // b*NBLK + blk
  const int blk = grp & (NBLK - 1);
  const int b = grp >> 8;
  const int t0 = blk * U_BLK;
  const float2* base = reinterpret_cast<const float2*>(proj);

  float2 knq[8];
#pragma unroll
  for (int c = 0; c < 8; ++c)
    knq[c] = base[(size_t)((t0 + c) * B_SZ + b) * 128 + lane];
  const float2 mine = base[(size_t)((t0 + a) * B_SZ + b) * 128 + lane];

  float row[8];
#pragma unroll
  for (int c = 0; c < 8; ++c) {
    const float lhs = (c > a) ? mine.x : mine.y;
    row[c] = wave_red(lhs * knq[c].x);
  }
  if (lane == 0) {
    float* dst = gram + ((size_t)grp * 64 + a * 8);
    float4 r0, r1;
    r0.x = row[0]; r0.y = row[1]; r0.z = row[2]; r0.w = row[3];
    r1.x = row[4]; r1.y = row[5]; r1.z = row[6]; r1.w = row[7];
    *reinterpret_cast<float4*>(dst) = r0;
    *reinterpret_cast<float4*>(dst + 4) = r1;
  }
}

// ---------------------------------------------------------------------------
// Kernel 4: scan — EXACT R6 structure (best measured: 377 us) with ONE delta:
// gram coefficients come from wave-uniform global loads (compiler emits
// s_load -> SGPRs; proven R10) instead of lane-held gv + 64 v_readlane.
// 256 blocks x 4 waves; block -> (b, i-group of 4); XCD-aligned b.
// 2-buffer LDS staging, 1 barrier/iter; factored UT-transform recurrence.
// ---------------------------------------------------------------------------
__global__ __launch_bounds__(256, 1) void scan_kernel(
    const float* __restrict__ proj, const float* __restrict__ gram,
    const float* __restrict__ S0, float* __restrict__ out,
    float* __restrict__ Sfin) {
  const int wid = threadIdx.x >> 6;     // 0..3
  const int lane = threadIdx.x & 63;
  const int bid = blockIdx.x;
  const int b = (bid & 7) | ((bid >> 7) << 3);     // same XCD for same b
  const int i = (((bid >> 3) & 15) << 2) | wid;

  __shared__ float lds[2][U_BLK * 256];   // 2 x 8 KB

  float S = S0[(size_t)b * 4096 + i * 64 + lane];

  const int r0 = wid * 2;           // this wave stages rows r0, r0+1
  float4 st0, st1;

#define STAGE_LOAD(blkv)                                                      \
  {                                                                           \
    const size_t g0 = ((size_t)(((blkv) * U_BLK + r0) * B_SZ + b)) * NOUT;    \
    st0 = *reinterpret_cast<const float4*>(&proj[g0 + lane * 4]);             \
    st1 = *reinterpret_cast<const float4*>(&proj[g0 + (size_t)B_SZ * NOUT +   \
                                                 lane * 4]);                  \
  }

#define STAGE_WRITE(bufv)                                                     \
  {                                                                           \
    *reinterpret_cast<float4*>(&lds[bufv][r0 * 256 + lane * 4]) = st0;        \
    *reinterpret_cast<float4*>(&lds[bufv][(r0 + 1) * 256 + lane * 4]) = st1;  \
  }

  STAGE_LOAD(0)
  STAGE_WRITE(0)
  __syncthreads();

  for (int blk = 0; blk < NBLK; ++blk) {
    const int buf = blk & 1;
    if (blk + 1 < NBLK) STAGE_LOAD(blk + 1)

    // gram scalars: wave-uniform address -> s_load into SGPRs (R10-proven)
    const float* gp = gram + (((size_t)b * NBLK + blk) << 6);
    float g[64];
#pragma unroll
    for (int z = 0; z < 64; ++z) g[z] = gp[z];

    // ---- compute block blk from lds[buf] ----
    float2 knqv[8], vdv[8];
#pragma unroll
    for (int u = 0; u < 8; ++u) {
      knqv[u] = *reinterpret_cast<const float2*>(&lds[buf][u * 256 + lane * 2]);
      vdv[u] = *reinterpret_cast<const float2*>(&lds[buf][u * 256 + 128 + i * 2]);
    }

    // prefix products + reciprocals
    float c[9], rc[8];
    c[0] = 1.f;
#pragma unroll
    for (int u = 0; u < 8; ++u) {
      c[u + 1] = c[u] * vdv[u].y;
      rc[u] = __builtin_amdgcn_rcpf(c[u + 1]);
    }

    float acc[8], sac[8];
#pragma unroll
    for (int u = 0; u < 8; ++u) acc[u] = wave_red(S * knqv[u].x);
#pragma unroll
    for (int u = 0; u < 8; ++u) sac[u] = wave_red(S * knqv[u].y);

    // factored UT-transform recurrence (verified R6)
    float dp[8], sqv[8];
#pragma unroll
    for (int w = 0; w < 8; ++w) {
      const float d = fmaf(-c[w], acc[w], vdv[w].x);
      dp[w] = d * rc[w];
      sqv[w] = fmaf(c[w + 1], sac[w], d * g[w * 8 + w]);
#pragma unroll
      for (int u = w + 1; u < 8; ++u) {
        acc[u] = fmaf(dp[w], g[w * 8 + u], acc[u]);   // G[w][u]
        sac[u] = fmaf(dp[w], g[u * 8 + w], sac[u]);   // H[u][w]
      }
    }
    float tacc = S;
#pragma unroll
    for (int w = 0; w < 8; ++w) tacc = fmaf(dp[w], knqv[w].x, tacc);
    S = c[8] * tacc;

    if (lane == 0) {
      const size_t ob = (size_t)blk * U_BLK * (B_SZ * N_SZ) + b * N_SZ + i;
#pragma unroll
      for (int u = 0; u < 8; ++u)
        out[ob + (size_t)u * (B_SZ * N_SZ)] = sqv[u];   // raw sq; silu later
    }
    // ---- end compute ----

    if (blk + 1 < NBLK) STAGE_WRITE(buf ^ 1)
    __syncthreads();
  }

  Sfin[(size_t)b * 4096 + i * 64 + lane] = S;
#undef STAGE_LOAD
#undef STAGE_WRITE
}

// ---------------------------------------------------------------------------
// Kernel 5: out <- sq^2 * sigmoid(sq).  2048*256*4 = 2,097,152 elems exactly.
// ---------------------------------------------------------------------------
__global__ __launch_bounds__(256) void silu_pp(float* __restrict__ o) {
  const size_t idx = ((size_t)blockIdx.x * 256 + threadIdx.x) * 4;
  float4 v = *reinterpret_cast<float4*>(&o[idx]);
  v.x = v.x * v.x * __fdividef(1.f, 1.f + __expf(-v.x));
  v.y = v.y * v.y * __fdividef(1.f, 1.f + __expf(-v.y));
  v.z = v.z * v.z * __fdividef(1.f, 1.f + __expf(-v.z));
  v.w = v.w * v.w * __fdividef(1.f, 1.f + __expf(-v.w));
  *reinterpret_cast<float4*>(&o[idx]) = v;
}

// ---------------------------------------------------------------------------
extern "C" void kernel_launch(void* const* d_in, const int* in_sizes, int n_in,
                              void* d_out, int out_size, void* d_ws, size_t ws_size,
                              hipStream_t stream) {
  const float* x      = (const float*)d_in[0];
  const float* S0     = (const float*)d_in[1];
  const float* W      = (const float*)d_in[2];
  const float* b_gate = (const float*)d_in[3];
  float* out  = (float*)d_out;
  float* proj = (float*)d_ws;                       // 33.55 MB
  float* gram = (float*)((char*)d_ws + (size_t)M_ROWS * NOUT * 4);  // +1 MB

  hipLaunchKernelGGL(gemm_proj, dim3(M_ROWS / 64), dim3(256), 0, stream,
                     x, W, proj);
  hipLaunchKernelGGL(norm_gate, dim3(M_ROWS / 4), dim3(256), 0, stream,
                     proj, b_gate);
  hipLaunchKernelGGL(gram_kernel, dim3(32768 / 4), dim3(256), 0, stream,
                     proj, gram);
  hipLaunchKernelGGL(scan_kernel, dim3(256), dim3(256), 0, stream,
                     proj, gram, S0, out, out + (size_t)T_STEPS * B_SZ * N_SZ);
  hipLaunchKernelGGL(silu_pp, dim3(2048), dim3(256), 0, stream, out);
}